// Round 24
// baseline (360.086 us; speedup 1.0000x reference)
//
#include <hip/hip_runtime.h>

// VectorQuantizer: z (32,256,32,32) f32, embedding (1024,256) f32.
// N=32768 rows (n = b*1024 + h*32 + w), D=256, K=1024.
// Out (f32, concat): z_q_st [8388608] (B,C,H,W), vq_loss [1], idx [32768].
// z_flat[n][c] = z[b*262144 + c*1024 + (n & 1023)]
//
// v21 = r21 geometry (32 rows/wave, block = 64 rows x 4 waves, wave
// (rowHalf,ntH) = 32 rows x 512 codes) with SINGLE-buffered tile streams:
// LDS = exactly 32768 B (2 streams x 16 KB) -> 2 blocks/CU co-reside
// (proven at 32KB by r19/r23; 64KB never co-resided, r21/r22). Two
// barriers/step; t+1 global loads issued before compute (latency hidden).
// Halves total B LDS-reads vs r23 (each B fragment feeds 6 MFMAs).
// Merge arrays alias dead tiles. Numerics identical to r21/r23 (absmax 0).
// prepK/refineK/outputK/finalK verbatim from r23.
// ws: [0] loss f64; [16) rcount; [64) enorm 4KB; [4352) bp (1MB both limbs);
//     [1052928) eT 1MB; [2494720) idx_buf; [2625792) rlist.

#define TAU 4.0e-4f

typedef __attribute__((ext_vector_type(8))) short short8b;   // 8 bf16
typedef __attribute__((ext_vector_type(4))) float f32x4;

__device__ __forceinline__ unsigned short f2bf_rne(float x) {
  unsigned int u = __float_as_uint(x);
  unsigned int r = u + 0x7fffu + ((u >> 16) & 1u);
  return (unsigned short)(r >> 16);
}
__device__ __forceinline__ float bf2f(unsigned short s) {
  return __uint_as_float(((unsigned int)s) << 16);
}

__device__ __forceinline__ float np_pairwise256_sq(const float* a) {
  float tot = 0.0f;
#pragma unroll
  for (int blk = 0; blk < 2; ++blk) {
    const float* p = a + blk * 128;
    float r[8];
#pragma unroll
    for (int j = 0; j < 8; ++j) r[j] = __fmul_rn(p[j], p[j]);
    for (int i = 8; i < 128; i += 8) {
#pragma unroll
      for (int j = 0; j < 8; ++j) r[j] = __fadd_rn(r[j], __fmul_rn(p[i + j], p[i + j]));
    }
    float res = __fadd_rn(__fadd_rn(__fadd_rn(r[0], r[1]), __fadd_rn(r[2], r[3])),
                          __fadd_rn(__fadd_rn(r[4], r[5]), __fadd_rn(r[6], r[7])));
    tot = (blk == 0) ? res : __fadd_rn(tot, res);
  }
  return tot;
}

// Fused prep: blocks 0-3 enorm, 4-259 eT transpose, 260-323 both-limb pack.
__global__ __launch_bounds__(256) void prepK(const float* __restrict__ emb,
                                             float* __restrict__ enorm,
                                             float* __restrict__ eT,
                                             unsigned short* __restrict__ bp,
                                             double* loss_sum, int* rcount) {
  __shared__ float tt[32][33];
  const int blk = blockIdx.x;
  const int t = threadIdx.x;
  if (blk == 0 && t == 0) { *loss_sum = 0.0; *rcount = 0; }
  if (blk < 4) {
    const int k = blk * 256 + t;
    enorm[k] = np_pairwise256_sq(emb + (size_t)k * 256);
  } else if (blk < 260) {
    const int local = blk - 4;
    const int k0 = (local & 31) * 32, d0 = (local >> 5) * 32;
    const int lx = t & 31, ly = t >> 5;
#pragma unroll
    for (int r = 0; r < 4; ++r)
      tt[ly + r * 8][lx] = emb[(size_t)(k0 + ly + r * 8) * 256 + d0 + lx];
    __syncthreads();
#pragma unroll
    for (int r = 0; r < 4; ++r)
      eT[(size_t)(d0 + ly + r * 8) * 1024 + k0 + lx] = tt[lx][ly + r * 8];
  } else {
    const int C = blk - 260;  // 64 code-blocks of 16
    const int n = t & 15, kb = (t >> 4) & 7, limb = t >> 7;
    const float* er = emb + (size_t)(C * 16 + n) * 256 + kb * 32;
#pragma unroll
    for (int s = 0; s < 4; ++s) {
      unsigned int w[4];
#pragma unroll
      for (int p = 0; p < 4; ++p) {
        unsigned short v2[2];
#pragma unroll
        for (int q = 0; q < 2; ++q) {
          float x = er[s * 8 + p * 2 + q];
          unsigned short hi = f2bf_rne(x);
          v2[q] = (limb == 0) ? hi : f2bf_rne(x - bf2f(hi));
        }
        w[p] = (unsigned int)v2[0] | ((unsigned int)v2[1] << 16);
      }
      size_t idx = ((size_t)(C * 16 + limb * 8 + kb) * 64 + (n + 16 * s)) * 8;
      *(uint4*)(bp + idx) = make_uint4(w[0], w[1], w[2], w[3]);
    }
  }
}

// MFMA distance pass: block = 64 rows x 4 waves; wave (rowHalf,ntH) covers
// 32 rows x 512 codes over 32 steps. Single-buffered 2-stream LDS (32 KB).
__global__ __launch_bounds__(256) void distK(const float* __restrict__ z,
                                             const unsigned short* __restrict__ bp,
                                             const float* __restrict__ enorm,
                                             int* __restrict__ idx_buf,
                                             float* __restrict__ out,
                                             int* __restrict__ rlist,
                                             int* __restrict__ rcount) {
  __shared__ unsigned short lds[2][8192];  // [stream], 32768 B total
  const int tid = threadIdx.x;
  const int wid = tid >> 6, lane = tid & 63;
  const int rowHalf = wid >> 1;   // which 32-row group
  const int ntH = wid & 1;        // which code half (nt stream)
  const int n0 = blockIdx.x * 64;
  const int n0w = n0 + rowHalf * 32;
  const int b = n0w >> 10, hw0 = n0w & 1023;  // 32 | 1024 -> no b straddle
  const int s = lane >> 4, m = lane & 15;
  const float* zb = z + (size_t)b * 262144 + hw0 + m;

  // A fragments: two 16-row tiles (rows +0, +16)
  short8b az0[8], al0[8], az1[8], al1[8];
#pragma unroll
  for (int kb = 0; kb < 8; ++kb) {
    float f0[8], f1[8];
#pragma unroll
    for (int i = 0; i < 8; ++i) {
      size_t off = (size_t)(kb * 32 + s * 8 + i) * 1024;
      f0[i] = zb[off];
      f1[i] = zb[off + 16];
    }
#pragma unroll
    for (int i = 0; i < 8; ++i) {
      unsigned short h0 = f2bf_rne(f0[i]);
      az0[kb][i] = (short)h0;
      al0[kb][i] = (short)f2bf_rne(f0[i] - bf2f(h0));
      unsigned short h1 = f2bf_rne(f1[i]);
      az1[kb][i] = (short)h1;
      al1[kb][i] = (short)f2bf_rne(f1[i] - bf2f(h1));
    }
  }

  float m1[2][4], m2[2][4];
  int k1i[2][4];
#pragma unroll
  for (int t = 0; t < 2; ++t)
#pragma unroll
    for (int r = 0; r < 4; ++r) { m1[t][r] = 3.0e38f; m2[t][r] = 3.0e38f; k1i[t][r] = 0; }

  const uint4* bpv = (const uint4*)bp;  // tile nt = granules [nt*1024, +1024)
  // prologue: stage t=0 tiles of both streams
#pragma unroll
  for (int h = 0; h < 2; ++h)
#pragma unroll
    for (int i = 0; i < 4; ++i)
      ((uint4*)lds[h])[i * 256 + tid] = bpv[(size_t)(h * 32) * 1024 + i * 256 + tid];
  __syncthreads();

  uint4 st[2][4];
  for (int t = 0; t < 32; ++t) {
    if (t < 31) {  // issue next tiles for both streams (hide under compute)
#pragma unroll
      for (int h = 0; h < 2; ++h)
#pragma unroll
        for (int i = 0; i < 4; ++i)
          st[h][i] = bpv[(size_t)(h * 32 + t + 1) * 1024 + i * 256 + tid];
    }
    const int nt = ntH * 32 + t;
    f32x4 a00 = {0, 0, 0, 0}, a01 = {0, 0, 0, 0}, a02 = {0, 0, 0, 0};
    f32x4 a10 = {0, 0, 0, 0}, a11 = {0, 0, 0, 0}, a12 = {0, 0, 0, 0};
    float en = enorm[nt * 16 + m];
    const unsigned short* tile = lds[ntH];
#pragma unroll
    for (int kb = 0; kb < 8; ++kb) {
      short8b eh = *(const short8b*)(tile + kb * 512 + lane * 8);
      short8b el = *(const short8b*)(tile + 4096 + kb * 512 + lane * 8);
      a00 = __builtin_amdgcn_mfma_f32_16x16x32_bf16(az0[kb], eh, a00, 0, 0, 0);
      a10 = __builtin_amdgcn_mfma_f32_16x16x32_bf16(az1[kb], eh, a10, 0, 0, 0);
      a01 = __builtin_amdgcn_mfma_f32_16x16x32_bf16(al0[kb], eh, a01, 0, 0, 0);
      a11 = __builtin_amdgcn_mfma_f32_16x16x32_bf16(al1[kb], eh, a11, 0, 0, 0);
      a02 = __builtin_amdgcn_mfma_f32_16x16x32_bf16(az0[kb], el, a02, 0, 0, 0);
      a12 = __builtin_amdgcn_mfma_f32_16x16x32_bf16(az1[kb], el, a12, 0, 0, 0);
    }
    const int code = nt * 16 + m;
#pragma unroll
    for (int r = 0; r < 4; ++r) {  // row tile 0: D row = s*4+r, col = m
      float v = en - 2.0f * ((a00[r] + a01[r]) + a02[r]);
      if (v < m1[0][r]) { m2[0][r] = m1[0][r]; m1[0][r] = v; k1i[0][r] = code; }
      else if (v < m2[0][r]) { m2[0][r] = v; }
    }
#pragma unroll
    for (int r = 0; r < 4; ++r) {  // row tile 1
      float v = en - 2.0f * ((a10[r] + a11[r]) + a12[r]);
      if (v < m1[1][r]) { m2[1][r] = m1[1][r]; m1[1][r] = v; k1i[1][r] = code; }
      else if (v < m2[1][r]) { m2[1][r] = v; }
    }
    __syncthreads();  // all waves done reading tile t
    if (t < 31) {     // write tile t+1 into the (single) buffers
#pragma unroll
      for (int h = 0; h < 2; ++h)
#pragma unroll
        for (int i = 0; i < 4; ++i)
          ((uint4*)lds[h])[i * 256 + tid] = st[h][i];
      __syncthreads();  // tile t+1 ready
    }
  }
  // tiles are dead now -> alias merge arrays
  float* sm1 = (float*)lds;            // [2][64]
  float* sm2 = sm1 + 128;              // [2][64]
  int* sk = (int*)(sm2 + 128);         // [2][64]

  // per-wave reduce across the 16 code-columns, stash per-stream results
#pragma unroll
  for (int t = 0; t < 2; ++t)
#pragma unroll
    for (int r = 0; r < 4; ++r) {
      float a1 = m1[t][r], a2 = m2[t][r];
      int ai = k1i[t][r];
#pragma unroll
      for (int mask = 1; mask < 16; mask <<= 1) {
        float b1 = __shfl_xor(a1, mask);
        float b2 = __shfl_xor(a2, mask);
        int bi = __shfl_xor(ai, mask);
        if (b1 < a1 || (b1 == a1 && bi < ai)) { a2 = fminf(a1, b2); a1 = b1; ai = bi; }
        else { a2 = fminf(a2, b1); }
      }
      if (m == 0) {
        int lr = rowHalf * 32 + t * 16 + s * 4 + r;
        sm1[ntH * 64 + lr] = a1;
        sm2[ntH * 64 + lr] = a2;
        sk[ntH * 64 + lr] = ai;
      }
    }
  __syncthreads();

  // merge the two code-halves per row (stream0 codes < stream1 -> tie keeps 0)
  if (tid < 64) {
    float a1 = sm1[tid], a2 = sm2[tid];
    int ai = sk[tid];
    float b1 = sm1[64 + tid], b2 = sm2[64 + tid];
    int bi = sk[64 + tid];
    if (b1 < a1) { a2 = fminf(a1, b2); a1 = b1; ai = bi; }
    else { a2 = fminf(a2, b1); }
    int n = n0 + tid;
    idx_buf[n] = ai;
    out[(size_t)8388609 + n] = (float)ai;
    if (a2 - a1 < TAU) {
      int p = atomicAdd(rcount, 1);
      rlist[p] = n;
    }
  }
}

// np-f32 bit-exact re-derivation: ONE WAVE PER BLOCK, rows spread across
// 2048 blocks (ii = blockIdx.x stride gridDim.x). Proven r16 structure.
__global__ __launch_bounds__(64) void refineK(const float* __restrict__ z,
                                              const float* __restrict__ eT,
                                              const float* __restrict__ enorm,
                                              const int* __restrict__ rlist,
                                              const int* __restrict__ rcount,
                                              int* __restrict__ idx_buf,
                                              float* __restrict__ out) {
  __shared__ float zw[256];  // single wave -> no barriers needed
  const int lane = threadIdx.x;
  const int cnt = *rcount;
  for (int ii = blockIdx.x; ii < cnt; ii += gridDim.x) {
    const int n = rlist[ii];
    const int bb = n >> 10, hw = n & 1023;
#pragma unroll
    for (int s = 0; s < 4; ++s)
      zw[lane + s * 64] = z[(size_t)bb * 262144 + (size_t)(lane + s * 64) * 1024 + hw];
    const float a32 = np_pairwise256_sq(zw);

    float bch[16];
#pragma unroll
    for (int j = 0; j < 16; ++j) bch[j] = 0.0f;
    const float* eb = eT + lane * 16;

    float4 B0[4], B1[4], B2[4], B3[4];
#pragma unroll
    for (int q = 0; q < 4; ++q) {
      B0[q] = *(const float4*)(eb + (size_t)0 * 1024 + q * 4);
      B1[q] = *(const float4*)(eb + (size_t)1 * 1024 + q * 4);
      B2[q] = *(const float4*)(eb + (size_t)2 * 1024 + q * 4);
      B3[q] = *(const float4*)(eb + (size_t)3 * 1024 + q * 4);
    }
#pragma unroll 1
    for (int d = 0; d < 256; d += 4) {
      const bool more = (d + 4) < 256;
      {
        float zv = zw[d];
#pragma unroll
        for (int q = 0; q < 4; ++q) {
          bch[q * 4 + 0] = __fmaf_rn(zv, B0[q].x, bch[q * 4 + 0]);
          bch[q * 4 + 1] = __fmaf_rn(zv, B0[q].y, bch[q * 4 + 1]);
          bch[q * 4 + 2] = __fmaf_rn(zv, B0[q].z, bch[q * 4 + 2]);
          bch[q * 4 + 3] = __fmaf_rn(zv, B0[q].w, bch[q * 4 + 3]);
        }
        if (more) {
#pragma unroll
          for (int q = 0; q < 4; ++q)
            B0[q] = *(const float4*)(eb + (size_t)(d + 4) * 1024 + q * 4);
        }
      }
      {
        float zv = zw[d + 1];
#pragma unroll
        for (int q = 0; q < 4; ++q) {
          bch[q * 4 + 0] = __fmaf_rn(zv, B1[q].x, bch[q * 4 + 0]);
          bch[q * 4 + 1] = __fmaf_rn(zv, B1[q].y, bch[q * 4 + 1]);
          bch[q * 4 + 2] = __fmaf_rn(zv, B1[q].z, bch[q * 4 + 2]);
          bch[q * 4 + 3] = __fmaf_rn(zv, B1[q].w, bch[q * 4 + 3]);
        }
        if (more) {
#pragma unroll
          for (int q = 0; q < 4; ++q)
            B1[q] = *(const float4*)(eb + (size_t)(d + 5) * 1024 + q * 4);
        }
      }
      {
        float zv = zw[d + 2];
#pragma unroll
        for (int q = 0; q < 4; ++q) {
          bch[q * 4 + 0] = __fmaf_rn(zv, B2[q].x, bch[q * 4 + 0]);
          bch[q * 4 + 1] = __fmaf_rn(zv, B2[q].y, bch[q * 4 + 1]);
          bch[q * 4 + 2] = __fmaf_rn(zv, B2[q].z, bch[q * 4 + 2]);
          bch[q * 4 + 3] = __fmaf_rn(zv, B2[q].w, bch[q * 4 + 3]);
        }
        if (more) {
#pragma unroll
          for (int q = 0; q < 4; ++q)
            B2[q] = *(const float4*)(eb + (size_t)(d + 6) * 1024 + q * 4);
        }
      }
      {
        float zv = zw[d + 3];
#pragma unroll
        for (int q = 0; q < 4; ++q) {
          bch[q * 4 + 0] = __fmaf_rn(zv, B3[q].x, bch[q * 4 + 0]);
          bch[q * 4 + 1] = __fmaf_rn(zv, B3[q].y, bch[q * 4 + 1]);
          bch[q * 4 + 2] = __fmaf_rn(zv, B3[q].z, bch[q * 4 + 2]);
          bch[q * 4 + 3] = __fmaf_rn(zv, B3[q].w, bch[q * 4 + 3]);
        }
        if (more) {
#pragma unroll
          for (int q = 0; q < 4; ++q)
            B3[q] = *(const float4*)(eb + (size_t)(d + 7) * 1024 + q * 4);
        }
      }
    }

    float best = 3.0e38f;
    int bi = 1 << 30;
#pragma unroll
    for (int j = 0; j < 16; ++j) {
      const int k = lane * 16 + j;  // ascending -> first-index wins
      float tb = __fmul_rn(2.0f, bch[j]);
      float d32 = __fadd_rn(__fsub_rn(a32, tb), enorm[k]);
      if (d32 < best) { best = d32; bi = k; }
    }
#pragma unroll
    for (int mask = 1; mask < 64; mask <<= 1) {
      float ov = __shfl_xor(best, mask);
      int oi = __shfl_xor(bi, mask);
      if (ov < best || (ov == best && oi < bi)) { best = ov; bi = oi; }
    }
    if (lane == 0) {
      idx_buf[n] = bi;
      out[(size_t)8388609 + n] = (float)bi;
    }
  }
}

// z_q gather + z_q_st write + loss (one loss atomic per block).
__global__ __launch_bounds__(256) void outputK(const float* __restrict__ z,
                                               const float* __restrict__ emb,
                                               const int* __restrict__ idx_buf,
                                               float* __restrict__ out,
                                               double* __restrict__ loss_sum) {
  __shared__ float el[64 * 65];  // [row][65] pad -> conflict-free staging
  __shared__ int sidx[64];
  __shared__ double sloss[4];

  const int tid = threadIdx.x;
  const int rg = blockIdx.x >> 2;
  const int q = blockIdx.x & 3;       // channel quarter
  const int n0 = rg * 64;
  const int b = n0 >> 10;
  const int hw0 = n0 & 1023;

  if (tid < 64) sidx[tid] = idx_buf[n0 + tid];
  __syncthreads();

#pragma unroll
  for (int rep = 0; rep < 16; ++rep) {
    int idx = rep * 256 + tid;
    int r = idx >> 6, i = idx & 63;
    el[r * 65 + i] = emb[(size_t)sidx[r] * 256 + q * 64 + i];
  }
  __syncthreads();

  const int mq = (tid & 15) * 4;      // m base (4 consecutive hw)
  const int cg = tid >> 4;            // 0..15
  const size_t zb = (size_t)b * 262144 + hw0 + mq;
  double acc = 0.0;
#pragma unroll
  for (int it = 0; it < 4; ++it) {
    int cl = it * 16 + cg;            // local channel 0..63
    int c = q * 64 + cl;
    float4 z4 = *(const float4*)(z + zb + (size_t)c * 1024);
    float e0 = el[(mq + 0) * 65 + cl];
    float e1 = el[(mq + 1) * 65 + cl];
    float e2 = el[(mq + 2) * 65 + cl];
    float e3 = el[(mq + 3) * 65 + cl];
    float d0 = e0 - z4.x, d1 = e1 - z4.y, d2 = e2 - z4.z, d3 = e3 - z4.w;
    float4 o = make_float4(z4.x + d0, z4.y + d1, z4.z + d2, z4.w + d3);
    *(float4*)(out + zb + (size_t)c * 1024) = o;
    acc += (double)(d0 * d0) + (double)(d1 * d1) +
           (double)(d2 * d2) + (double)(d3 * d3);
  }
  for (int mask = 1; mask < 64; mask <<= 1) acc += __shfl_xor(acc, mask);
  if ((tid & 63) == 0) sloss[tid >> 6] = acc;
  __syncthreads();
  if (tid == 0)
    atomicAdd(loss_sum, sloss[0] + sloss[1] + sloss[2] + sloss[3]);
}

__global__ void finalK(const double* loss_sum, float* out) {
  double s = *loss_sum;
  out[8388608] = (float)(1.25 * s / 8388608.0);  // (1+beta)*mean, beta=0.25
}

extern "C" void kernel_launch(void* const* d_in, const int* in_sizes, int n_in,
                              void* d_out, int out_size, void* d_ws, size_t ws_size,
                              hipStream_t stream) {
  const float* z = (const float*)d_in[0];
  const float* emb = (const float*)d_in[1];
  float* out = (float*)d_out;
  char* ws = (char*)d_ws;
  double* loss_sum = (double*)ws;
  int* rcount = (int*)(ws + 16);
  float* enorm = (float*)(ws + 64);
  unsigned short* bp = (unsigned short*)(ws + 4352);  // 1 MB (both limbs)
  float* eT = (float*)(ws + 1052928);                 // 1 MB
  int* idx_buf = (int*)(ws + 2494720);
  int* rlist = (int*)(ws + 2625792);

  prepK<<<324, 256, 0, stream>>>(emb, enorm, eT, bp, loss_sum, rcount);
  distK<<<512, 256, 0, stream>>>(z, bp, enorm, idx_buf, out, rlist, rcount);
  refineK<<<2048, 64, 0, stream>>>(z, eT, enorm, rlist, rcount, idx_buf, out);
  outputK<<<2048, 256, 0, stream>>>(z, emb, idx_buf, out, loss_sum);
  finalK<<<1, 1, 0, stream>>>(loss_sum, out);
}

// Round 25
// 185.007 us; speedup vs baseline: 1.9463x; 1.9463x over previous
//
#include <hip/hip_runtime.h>

// VectorQuantizer: z (32,256,32,32) f32, embedding (1024,256) f32.
// N=32768 rows (n = b*1024 + h*32 + w), D=256, K=1024.
// Out (f32, concat): z_q_st [8388608] (B,C,H,W), vq_loss [1], idx [32768].
// z_flat[n][c] = z[b*262144 + c*1024 + (n & 1023)]
//
// FINAL = r23 (best measured: 185.6us, absmax 0):
//  - distK: 16 rows/wave, 2x16KB LDS dbuf shared by 4 waves, 3 independent
//    MFMA chains (zh*eh + zl*eh + zh*el), fused epilogue. ~95us, Occ 21%.
//    (Plateau: L2-direct/LDS/acc-ILP/32-row variants all >= 94us; 32-row
//    designs failed on occupancy (64KB LDS no co-residency) or spill.)
//  - fused prepK (enorm + eT transpose + limb pack), spread refineK
//    (np-f32 bit-exact, TAU=4e-4, wave-per-row over 2048 blocks),
//    vectorized outputK (LDS emb staging, float4 z/out), separate finalK.
// ws: [0] loss f64; [16) rcount; [64) enorm 4KB; [4352) bp (1MB both limbs);
//     [1052928) eT 1MB; [2494720) idx_buf; [2625792) rlist.

#define TAU 4.0e-4f

typedef __attribute__((ext_vector_type(8))) short short8b;   // 8 bf16
typedef __attribute__((ext_vector_type(4))) float f32x4;

__device__ __forceinline__ unsigned short f2bf_rne(float x) {
  unsigned int u = __float_as_uint(x);
  unsigned int r = u + 0x7fffu + ((u >> 16) & 1u);
  return (unsigned short)(r >> 16);
}
__device__ __forceinline__ float bf2f(unsigned short s) {
  return __uint_as_float(((unsigned int)s) << 16);
}

__device__ __forceinline__ float np_pairwise256_sq(const float* a) {
  float tot = 0.0f;
#pragma unroll
  for (int blk = 0; blk < 2; ++blk) {
    const float* p = a + blk * 128;
    float r[8];
#pragma unroll
    for (int j = 0; j < 8; ++j) r[j] = __fmul_rn(p[j], p[j]);
    for (int i = 8; i < 128; i += 8) {
#pragma unroll
      for (int j = 0; j < 8; ++j) r[j] = __fadd_rn(r[j], __fmul_rn(p[i + j], p[i + j]));
    }
    float res = __fadd_rn(__fadd_rn(__fadd_rn(r[0], r[1]), __fadd_rn(r[2], r[3])),
                          __fadd_rn(__fadd_rn(r[4], r[5]), __fadd_rn(r[6], r[7])));
    tot = (blk == 0) ? res : __fadd_rn(tot, res);
  }
  return tot;
}

// Fused prep: blocks 0-3 enorm, 4-259 eT transpose, 260-323 both-limb pack.
__global__ __launch_bounds__(256) void prepK(const float* __restrict__ emb,
                                             float* __restrict__ enorm,
                                             float* __restrict__ eT,
                                             unsigned short* __restrict__ bp,
                                             double* loss_sum, int* rcount) {
  __shared__ float tt[32][33];
  const int blk = blockIdx.x;
  const int t = threadIdx.x;
  if (blk == 0 && t == 0) { *loss_sum = 0.0; *rcount = 0; }
  if (blk < 4) {
    const int k = blk * 256 + t;
    enorm[k] = np_pairwise256_sq(emb + (size_t)k * 256);
  } else if (blk < 260) {
    const int local = blk - 4;
    const int k0 = (local & 31) * 32, d0 = (local >> 5) * 32;
    const int lx = t & 31, ly = t >> 5;
#pragma unroll
    for (int r = 0; r < 4; ++r)
      tt[ly + r * 8][lx] = emb[(size_t)(k0 + ly + r * 8) * 256 + d0 + lx];
    __syncthreads();
#pragma unroll
    for (int r = 0; r < 4; ++r)
      eT[(size_t)(d0 + ly + r * 8) * 1024 + k0 + lx] = tt[lx][ly + r * 8];
  } else {
    const int C = blk - 260;  // 64 code-blocks of 16
    const int n = t & 15, kb = (t >> 4) & 7, limb = t >> 7;
    const float* er = emb + (size_t)(C * 16 + n) * 256 + kb * 32;
#pragma unroll
    for (int s = 0; s < 4; ++s) {
      unsigned int w[4];
#pragma unroll
      for (int p = 0; p < 4; ++p) {
        unsigned short v2[2];
#pragma unroll
        for (int q = 0; q < 2; ++q) {
          float x = er[s * 8 + p * 2 + q];
          unsigned short hi = f2bf_rne(x);
          v2[q] = (limb == 0) ? hi : f2bf_rne(x - bf2f(hi));
        }
        w[p] = (unsigned int)v2[0] | ((unsigned int)v2[1] << 16);
      }
      size_t idx = ((size_t)(C * 16 + limb * 8 + kb) * 64 + (n + 16 * s)) * 8;
      *(uint4*)(bp + idx) = make_uint4(w[0], w[1], w[2], w[3]);
    }
  }
}

// MFMA distance pass (3 INDEPENDENT chains), B-tile in LDS shared by 4 waves.
// wave = 16 rows x 1024 codes; fused epilogue writes idx/out + rlist.
__global__ __launch_bounds__(256) void distK(const float* __restrict__ z,
                                             const unsigned short* __restrict__ bp,
                                             const float* __restrict__ enorm,
                                             int* __restrict__ idx_buf,
                                             float* __restrict__ out,
                                             int* __restrict__ rlist,
                                             int* __restrict__ rcount) {
  __shared__ unsigned short lds[2][8192];  // 2 x 16 KB
  const int tid = threadIdx.x;
  const int wid = tid >> 6, lane = tid & 63;
  const int R = blockIdx.x * 4 + wid;  // 2048 row-blocks of 16
  const int n0w = R * 16;
  const int b = n0w >> 10, hw0 = n0w & 1023;
  const int s = lane >> 4, m = lane & 15;
  const float* zb = z + (size_t)b * 262144 + hw0 + m;

  short8b az[8], al[8];
#pragma unroll
  for (int kb = 0; kb < 8; ++kb) {
    float f[8];
#pragma unroll
    for (int i = 0; i < 8; ++i)
      f[i] = zb[(size_t)(kb * 32 + s * 8 + i) * 1024];
#pragma unroll
    for (int i = 0; i < 8; ++i) {
      unsigned short hi = f2bf_rne(f[i]);
      az[kb][i] = (short)hi;
      al[kb][i] = (short)f2bf_rne(f[i] - bf2f(hi));
    }
  }

  float m1[4], m2[4];
  int k1i[4];
#pragma unroll
  for (int r = 0; r < 4; ++r) { m1[r] = 3.0e38f; m2[r] = 3.0e38f; k1i[r] = 0; }

  // stage tile 0: thread t covers 16-B granules t + i*256 (i=0..3)
  const uint4* bpv = (const uint4*)bp;  // tile nt = granules [nt*1024, +1024)
  uint4 st[4];
#pragma unroll
  for (int i = 0; i < 4; ++i) st[i] = bpv[i * 256 + tid];
#pragma unroll
  for (int i = 0; i < 4; ++i) ((uint4*)lds[0])[i * 256 + tid] = st[i];
  __syncthreads();

  int cur = 0;
  for (int nt = 0; nt < 64; ++nt) {
    if (nt < 63) {  // issue next tile's global loads (hide under compute)
#pragma unroll
      for (int i = 0; i < 4; ++i)
        st[i] = bpv[(size_t)(nt + 1) * 1024 + i * 256 + tid];
    }
    f32x4 acc0 = {0.0f, 0.0f, 0.0f, 0.0f};
    f32x4 acc1 = {0.0f, 0.0f, 0.0f, 0.0f};
    f32x4 acc2 = {0.0f, 0.0f, 0.0f, 0.0f};
    float en = enorm[nt * 16 + m];
    const unsigned short* tile = lds[cur];
#pragma unroll
    for (int kb = 0; kb < 8; ++kb) {
      short8b eh = *(const short8b*)(tile + kb * 512 + lane * 8);
      short8b el = *(const short8b*)(tile + 4096 + kb * 512 + lane * 8);
      acc0 = __builtin_amdgcn_mfma_f32_16x16x32_bf16(az[kb], eh, acc0, 0, 0, 0);
      acc1 = __builtin_amdgcn_mfma_f32_16x16x32_bf16(al[kb], eh, acc1, 0, 0, 0);
      acc2 = __builtin_amdgcn_mfma_f32_16x16x32_bf16(az[kb], el, acc2, 0, 0, 0);
    }
    const int code = nt * 16 + m;
#pragma unroll
    for (int r = 0; r < 4; ++r) {  // D row = s*4 + r, col = m
      float v = en - 2.0f * ((acc0[r] + acc1[r]) + acc2[r]);
      if (v < m1[r]) { m2[r] = m1[r]; m1[r] = v; k1i[r] = code; }
      else if (v < m2[r]) { m2[r] = v; }
    }
    if (nt < 63) {  // write prefetched tile into the other buffer
#pragma unroll
      for (int i = 0; i < 4; ++i) ((uint4*)lds[cur ^ 1])[i * 256 + tid] = st[i];
    }
    __syncthreads();
    cur ^= 1;
  }

#pragma unroll
  for (int r = 0; r < 4; ++r) {
    float a1 = m1[r], a2 = m2[r];
    int ai = k1i[r];
#pragma unroll
    for (int mask = 1; mask < 16; mask <<= 1) {
      float b1 = __shfl_xor(a1, mask);
      float b2 = __shfl_xor(a2, mask);
      int bi = __shfl_xor(ai, mask);
      if (b1 < a1 || (b1 == a1 && bi < ai)) { a2 = fminf(a1, b2); a1 = b1; ai = bi; }
      else { a2 = fminf(a2, b1); }
    }
    if (m == 0) {
      int n = n0w + s * 4 + r;
      idx_buf[n] = ai;
      out[(size_t)8388609 + n] = (float)ai;
      if (a2 - a1 < TAU) {
        int p = atomicAdd(rcount, 1);
        rlist[p] = n;
      }
    }
  }
}

// np-f32 bit-exact re-derivation: ONE WAVE PER BLOCK, rows spread across
// 2048 blocks (ii = blockIdx.x stride gridDim.x). Proven r16 structure.
__global__ __launch_bounds__(64) void refineK(const float* __restrict__ z,
                                              const float* __restrict__ eT,
                                              const float* __restrict__ enorm,
                                              const int* __restrict__ rlist,
                                              const int* __restrict__ rcount,
                                              int* __restrict__ idx_buf,
                                              float* __restrict__ out) {
  __shared__ float zw[256];  // single wave -> no barriers needed
  const int lane = threadIdx.x;
  const int cnt = *rcount;
  for (int ii = blockIdx.x; ii < cnt; ii += gridDim.x) {
    const int n = rlist[ii];
    const int bb = n >> 10, hw = n & 1023;
#pragma unroll
    for (int s = 0; s < 4; ++s)
      zw[lane + s * 64] = z[(size_t)bb * 262144 + (size_t)(lane + s * 64) * 1024 + hw];
    const float a32 = np_pairwise256_sq(zw);

    float bch[16];
#pragma unroll
    for (int j = 0; j < 16; ++j) bch[j] = 0.0f;
    const float* eb = eT + lane * 16;

    float4 B0[4], B1[4], B2[4], B3[4];
#pragma unroll
    for (int q = 0; q < 4; ++q) {
      B0[q] = *(const float4*)(eb + (size_t)0 * 1024 + q * 4);
      B1[q] = *(const float4*)(eb + (size_t)1 * 1024 + q * 4);
      B2[q] = *(const float4*)(eb + (size_t)2 * 1024 + q * 4);
      B3[q] = *(const float4*)(eb + (size_t)3 * 1024 + q * 4);
    }
#pragma unroll 1
    for (int d = 0; d < 256; d += 4) {
      const bool more = (d + 4) < 256;
      {
        float zv = zw[d];
#pragma unroll
        for (int q = 0; q < 4; ++q) {
          bch[q * 4 + 0] = __fmaf_rn(zv, B0[q].x, bch[q * 4 + 0]);
          bch[q * 4 + 1] = __fmaf_rn(zv, B0[q].y, bch[q * 4 + 1]);
          bch[q * 4 + 2] = __fmaf_rn(zv, B0[q].z, bch[q * 4 + 2]);
          bch[q * 4 + 3] = __fmaf_rn(zv, B0[q].w, bch[q * 4 + 3]);
        }
        if (more) {
#pragma unroll
          for (int q = 0; q < 4; ++q)
            B0[q] = *(const float4*)(eb + (size_t)(d + 4) * 1024 + q * 4);
        }
      }
      {
        float zv = zw[d + 1];
#pragma unroll
        for (int q = 0; q < 4; ++q) {
          bch[q * 4 + 0] = __fmaf_rn(zv, B1[q].x, bch[q * 4 + 0]);
          bch[q * 4 + 1] = __fmaf_rn(zv, B1[q].y, bch[q * 4 + 1]);
          bch[q * 4 + 2] = __fmaf_rn(zv, B1[q].z, bch[q * 4 + 2]);
          bch[q * 4 + 3] = __fmaf_rn(zv, B1[q].w, bch[q * 4 + 3]);
        }
        if (more) {
#pragma unroll
          for (int q = 0; q < 4; ++q)
            B1[q] = *(const float4*)(eb + (size_t)(d + 5) * 1024 + q * 4);
        }
      }
      {
        float zv = zw[d + 2];
#pragma unroll
        for (int q = 0; q < 4; ++q) {
          bch[q * 4 + 0] = __fmaf_rn(zv, B2[q].x, bch[q * 4 + 0]);
          bch[q * 4 + 1] = __fmaf_rn(zv, B2[q].y, bch[q * 4 + 1]);
          bch[q * 4 + 2] = __fmaf_rn(zv, B2[q].z, bch[q * 4 + 2]);
          bch[q * 4 + 3] = __fmaf_rn(zv, B2[q].w, bch[q * 4 + 3]);
        }
        if (more) {
#pragma unroll
          for (int q = 0; q < 4; ++q)
            B2[q] = *(const float4*)(eb + (size_t)(d + 6) * 1024 + q * 4);
        }
      }
      {
        float zv = zw[d + 3];
#pragma unroll
        for (int q = 0; q < 4; ++q) {
          bch[q * 4 + 0] = __fmaf_rn(zv, B3[q].x, bch[q * 4 + 0]);
          bch[q * 4 + 1] = __fmaf_rn(zv, B3[q].y, bch[q * 4 + 1]);
          bch[q * 4 + 2] = __fmaf_rn(zv, B3[q].z, bch[q * 4 + 2]);
          bch[q * 4 + 3] = __fmaf_rn(zv, B3[q].w, bch[q * 4 + 3]);
        }
        if (more) {
#pragma unroll
          for (int q = 0; q < 4; ++q)
            B3[q] = *(const float4*)(eb + (size_t)(d + 7) * 1024 + q * 4);
        }
      }
    }

    float best = 3.0e38f;
    int bi = 1 << 30;
#pragma unroll
    for (int j = 0; j < 16; ++j) {
      const int k = lane * 16 + j;  // ascending -> first-index wins
      float tb = __fmul_rn(2.0f, bch[j]);
      float d32 = __fadd_rn(__fsub_rn(a32, tb), enorm[k]);
      if (d32 < best) { best = d32; bi = k; }
    }
#pragma unroll
    for (int mask = 1; mask < 64; mask <<= 1) {
      float ov = __shfl_xor(best, mask);
      int oi = __shfl_xor(bi, mask);
      if (ov < best || (ov == best && oi < bi)) { best = ov; bi = oi; }
    }
    if (lane == 0) {
      idx_buf[n] = bi;
      out[(size_t)8388609 + n] = (float)bi;
    }
  }
}

// z_q gather + z_q_st write + loss (one loss atomic per block).
__global__ __launch_bounds__(256) void outputK(const float* __restrict__ z,
                                               const float* __restrict__ emb,
                                               const int* __restrict__ idx_buf,
                                               float* __restrict__ out,
                                               double* __restrict__ loss_sum) {
  __shared__ float el[64 * 65];  // [row][65] pad -> conflict-free staging
  __shared__ int sidx[64];
  __shared__ double sloss[4];

  const int tid = threadIdx.x;
  const int rg = blockIdx.x >> 2;
  const int q = blockIdx.x & 3;       // channel quarter
  const int n0 = rg * 64;
  const int b = n0 >> 10;
  const int hw0 = n0 & 1023;

  if (tid < 64) sidx[tid] = idx_buf[n0 + tid];
  __syncthreads();

#pragma unroll
  for (int rep = 0; rep < 16; ++rep) {
    int idx = rep * 256 + tid;
    int r = idx >> 6, i = idx & 63;
    el[r * 65 + i] = emb[(size_t)sidx[r] * 256 + q * 64 + i];
  }
  __syncthreads();

  const int mq = (tid & 15) * 4;      // m base (4 consecutive hw)
  const int cg = tid >> 4;            // 0..15
  const size_t zb = (size_t)b * 262144 + hw0 + mq;
  double acc = 0.0;
#pragma unroll
  for (int it = 0; it < 4; ++it) {
    int cl = it * 16 + cg;            // local channel 0..63
    int c = q * 64 + cl;
    float4 z4 = *(const float4*)(z + zb + (size_t)c * 1024);
    float e0 = el[(mq + 0) * 65 + cl];
    float e1 = el[(mq + 1) * 65 + cl];
    float e2 = el[(mq + 2) * 65 + cl];
    float e3 = el[(mq + 3) * 65 + cl];
    float d0 = e0 - z4.x, d1 = e1 - z4.y, d2 = e2 - z4.z, d3 = e3 - z4.w;
    float4 o = make_float4(z4.x + d0, z4.y + d1, z4.z + d2, z4.w + d3);
    *(float4*)(out + zb + (size_t)c * 1024) = o;
    acc += (double)(d0 * d0) + (double)(d1 * d1) +
           (double)(d2 * d2) + (double)(d3 * d3);
  }
  for (int mask = 1; mask < 64; mask <<= 1) acc += __shfl_xor(acc, mask);
  if ((tid & 63) == 0) sloss[tid >> 6] = acc;
  __syncthreads();
  if (tid == 0)
    atomicAdd(loss_sum, sloss[0] + sloss[1] + sloss[2] + sloss[3]);
}

__global__ void finalK(const double* loss_sum, float* out) {
  double s = *loss_sum;
  out[8388608] = (float)(1.25 * s / 8388608.0);  // (1+beta)*mean, beta=0.25
}

extern "C" void kernel_launch(void* const* d_in, const int* in_sizes, int n_in,
                              void* d_out, int out_size, void* d_ws, size_t ws_size,
                              hipStream_t stream) {
  const float* z = (const float*)d_in[0];
  const float* emb = (const float*)d_in[1];
  float* out = (float*)d_out;
  char* ws = (char*)d_ws;
  double* loss_sum = (double*)ws;
  int* rcount = (int*)(ws + 16);
  float* enorm = (float*)(ws + 64);
  unsigned short* bp = (unsigned short*)(ws + 4352);  // 1 MB (both limbs)
  float* eT = (float*)(ws + 1052928);                 // 1 MB
  int* idx_buf = (int*)(ws + 2494720);
  int* rlist = (int*)(ws + 2625792);

  prepK<<<324, 256, 0, stream>>>(emb, enorm, eT, bp, loss_sum, rcount);
  distK<<<512, 256, 0, stream>>>(z, bp, enorm, idx_buf, out, rlist, rcount);
  refineK<<<2048, 64, 0, stream>>>(z, eT, enorm, rlist, rcount, idx_buf, out);
  outputK<<<2048, 256, 0, stream>>>(z, emb, idx_buf, out, loss_sum);
  finalK<<<1, 1, 0, stream>>>(loss_sum, out);
}